// Round 2
// baseline (1208.715 us; speedup 1.0000x reference)
//
#include <hip/hip_runtime.h>

// ---------------- problem constants ----------------
#define NBATCH 32
#define LSEQ   2048
#define CDIM   256
#define KDIM   1024
#define DEMI   8
#define H1DIM  40
#define DEMO   20
#define NCHUNK 64
#define CHLEN  32
#define LNEPS  1e-5f

// ---- ws layout (float element offsets) ----
#define OFF_X    0L            // 32*2048*256 = 16777216 (X, overwritten in-place by p_max)
#define OFF_AGM  16777216L     // 32*64*256 = 524288
#define OFF_AGS  17301504L
#define OFF_AGI  17825792L     // int
#define OFF_PRM  18350080L
#define OFF_PRS  18874368L
#define OFF_PRI  19398656L     // int
#define OFF_DV   19922944L     // 32*20
#define OFF_BASE 19923584L     // 32*256
// total ~19931776 floats = 79.7 MB

// ---- d_out sections (float element offsets) ----
#define OUT0_OFF   0L          // [32,2048,788]
#define OUTTI_OFF  51642368L   // [32,256,2048]
#define OUTACT_OFF 68419584L   // [32,256,2048]

// ---------------------------------------------------------------------------
// K1: dem MLP (8->40->20, ReLU) + fold dem & b_lin into per-(n,c) base
// ---------------------------------------------------------------------------
__global__ __launch_bounds__(256) void k_dem(
    const float* __restrict__ dem,
    const float* __restrict__ W1, const float* __restrict__ b1,
    const float* __restrict__ W2, const float* __restrict__ b2,
    const float* __restrict__ Wl, const float* __restrict__ bl,
    float* __restrict__ dvals, float* __restrict__ base)
{
    __shared__ float h1[NBATCH][H1DIM];
    __shared__ float dsh[NBATCH][DEMO];
    int tid = threadIdx.x;

    for (int idx = tid; idx < NBATCH * H1DIM; idx += 256) {
        int n = idx / H1DIM, o = idx % H1DIM;
        float s = b1[o];
        #pragma unroll
        for (int k = 0; k < DEMI; ++k) s += dem[n * DEMI + k] * W1[k * H1DIM + o];
        h1[n][o] = fmaxf(s, 0.0f);
    }
    __syncthreads();
    for (int idx = tid; idx < NBATCH * DEMO; idx += 256) {
        int n = idx / DEMO, o = idx % DEMO;
        float s = b2[o];
        #pragma unroll
        for (int k = 0; k < H1DIM; ++k) s += h1[n][k] * W2[k * DEMO + o];
        float dv = fmaxf(s, 0.0f);
        dsh[n][o] = dv;
        dvals[idx] = dv;
    }
    __syncthreads();
    for (int idx = tid; idx < NBATCH * CDIM; idx += 256) {
        int n = idx >> 8, c = idx & 255;
        float s = bl[c];
        #pragma unroll
        for (int k = 0; k < DEMO; ++k) s += dsh[n][k] * Wl[(KDIM + k) * CDIM + c];
        base[idx] = s;
    }
}

// ---------------------------------------------------------------------------
// K2: fp32 GEMM  X[n,t,c] = sum_j ts[n,t,j] * W[j,c] + base[n,c]
//     M=65536, N=256, K=1024. BM=64 x BN=256, BK=32, 256 thr, 4x16/thread.
//     launch_bounds(256,2): VGPR cap 256 (64-reg spill observed at default).
//     As column-swizzled (m ^ ((k>>2)&3)<<3): staging writes 8-way -> 2-way.
//     Epilogue: per-32-t-chunk max/argmax/sum aggregates (replaces k_agg).
// ---------------------------------------------------------------------------
__global__ __launch_bounds__(256, 2) void k_gemm(
    const float* __restrict__ ts0, const float* __restrict__ ts1,
    const float* __restrict__ ts2, const float* __restrict__ ts3,
    const float* __restrict__ W, const float* __restrict__ base,
    float* __restrict__ X,
    float* __restrict__ agm, float* __restrict__ ags, int* __restrict__ agi)
{
    __shared__ float As[32][64];    // [k][m], column-swizzled
    __shared__ float Bs[32][256];   // [k][c]

    int tid = threadIdx.x;
    int n  = blockIdx.x >> 5;
    int t0 = (blockIdx.x & 31) << 6;
    int tm = tid & 15;          // m group: rows tm*4 .. tm*4+3
    int tn = tid >> 4;          // c group: cols tn*16 .. tn*16+15

    float acc[4][16];
    #pragma unroll
    for (int i = 0; i < 4; ++i)
        #pragma unroll
        for (int j = 0; j < 16; ++j) acc[i][j] = 0.0f;

    const long rowbase = ((long)n * LSEQ + t0) * CDIM;

    int lm = tid >> 3;          // 0..31 (A load row)
    int lkg = tid & 7;          // 0..7  (A load k-group of 4)
    int swz = (lkg & 3) << 3;   // write-side column swizzle

    for (int k0 = 0; k0 < KDIM; k0 += 32) {
        const float* tsp = (k0 < 256) ? ts0 : (k0 < 512) ? ts1 : (k0 < 768) ? ts2 : ts3;
        int joff = k0 & 255;

        float4 av0 = *(const float4*)(tsp + rowbase + (long)lm * CDIM + joff + lkg * 4);
        float4 av1 = *(const float4*)(tsp + rowbase + (long)(lm + 32) * CDIM + joff + lkg * 4);
        float4 bv[8];
        #pragma unroll
        for (int r = 0; r < 8; ++r) {
            int idx = tid + r * 256;
            int kk = idx >> 6, cg = idx & 63;
            bv[r] = *(const float4*)(W + (long)(k0 + kk) * CDIM + cg * 4);
        }

        __syncthreads();   // previous tile fully consumed
        As[lkg * 4 + 0][lm ^ swz] = av0.x;
        As[lkg * 4 + 1][lm ^ swz] = av0.y;
        As[lkg * 4 + 2][lm ^ swz] = av0.z;
        As[lkg * 4 + 3][lm ^ swz] = av0.w;
        As[lkg * 4 + 0][(lm + 32) ^ swz] = av1.x;
        As[lkg * 4 + 1][(lm + 32) ^ swz] = av1.y;
        As[lkg * 4 + 2][(lm + 32) ^ swz] = av1.z;
        As[lkg * 4 + 3][(lm + 32) ^ swz] = av1.w;
        #pragma unroll
        for (int r = 0; r < 8; ++r) {
            int idx = tid + r * 256;
            int kk = idx >> 6, cg = idx & 63;
            *(float4*)&Bs[kk][cg * 4] = bv[r];
        }
        __syncthreads();

        #pragma unroll 4
        for (int kk = 0; kk < 32; ++kk) {
            int rsw = ((kk >> 2) & 3) << 3;
            float4 a  = *(const float4*)&As[kk][(tm * 4) ^ rsw];
            float4 b0 = *(const float4*)&Bs[kk][tn * 16 + 0];
            float4 b1 = *(const float4*)&Bs[kk][tn * 16 + 4];
            float4 b2 = *(const float4*)&Bs[kk][tn * 16 + 8];
            float4 b3 = *(const float4*)&Bs[kk][tn * 16 + 12];
            const float am[4] = {a.x, a.y, a.z, a.w};
            const float bc[16] = {b0.x, b0.y, b0.z, b0.w, b1.x, b1.y, b1.z, b1.w,
                                  b2.x, b2.y, b2.z, b2.w, b3.x, b3.y, b3.z, b3.w};
            #pragma unroll
            for (int mi = 0; mi < 4; ++mi)
                #pragma unroll
                for (int j = 0; j < 16; ++j)
                    acc[mi][j] = fmaf(am[mi], bc[j], acc[mi][j]);
        }
    }

    // ---- epilogue: add base, write X, build per-chunk aggregates ----
    float bb[16];
    #pragma unroll
    for (int j = 0; j < 16; ++j) bb[j] = base[n * CDIM + tn * 16 + j];

    float vmx[16]; int vix[16]; float vsm[16];
    #pragma unroll
    for (int j = 0; j < 16; ++j) { vmx[j] = -3.4e38f; vix[j] = 0; vsm[j] = 0.0f; }

    #pragma unroll
    for (int mi = 0; mi < 4; ++mi) {
        int t = t0 + tm * 4 + mi;
        long row = rowbase + (long)(tm * 4 + mi) * CDIM;
        #pragma unroll
        for (int e = 0; e < 4; ++e) {
            float4 v;
            v.x = acc[mi][e * 4 + 0] + bb[e * 4 + 0];
            v.y = acc[mi][e * 4 + 1] + bb[e * 4 + 1];
            v.z = acc[mi][e * 4 + 2] + bb[e * 4 + 2];
            v.w = acc[mi][e * 4 + 3] + bb[e * 4 + 3];
            *(float4*)(X + row + tn * 16 + e * 4) = v;
            const float vv[4] = {v.x, v.y, v.z, v.w};
            #pragma unroll
            for (int q = 0; q < 4; ++q) {
                int j = e * 4 + q;
                if (vv[q] > vmx[j]) { vmx[j] = vv[q]; vix[j] = t; }
                vsm[j] += vv[q];
            }
        }
    }

    // reduce across the 8 tm's of this 32-t chunk (lanes tn*16 + tm, same wave)
    #pragma unroll
    for (int off = 1; off < 8; off <<= 1) {
        #pragma unroll
        for (int j = 0; j < 16; ++j) {
            float ov = __shfl_xor(vmx[j], off);
            int   oi = __shfl_xor(vix[j], off);
            float os = __shfl_xor(vsm[j], off);
            bool keep = (vmx[j] > ov) || (vmx[j] == ov && vix[j] <= oi);
            vmx[j] = keep ? vmx[j] : ov;
            vix[j] = keep ? vix[j] : oi;
            vsm[j] += os;
        }
    }

    int sub = tm & 7;
    int ch2 = ((blockIdx.x & 31) << 1) + (tm >> 3);
    long o = ((long)(n * NCHUNK + ch2) * CDIM) + tn * 16;
    agm[o + sub * 2 + 0] = vmx[sub * 2 + 0];
    agm[o + sub * 2 + 1] = vmx[sub * 2 + 1];
    ags[o + sub * 2 + 0] = vsm[sub * 2 + 0];
    ags[o + sub * 2 + 1] = vsm[sub * 2 + 1];
    agi[o + sub * 2 + 0] = vix[sub * 2 + 0];
    agi[o + sub * 2 + 1] = vix[sub * 2 + 1];
}

// ---------------------------------------------------------------------------
// K3: exclusive prefix over 64 chunks per (n,c), float4 over c
// ---------------------------------------------------------------------------
__global__ __launch_bounds__(256) void k_pre(
    const float* __restrict__ agm, const float* __restrict__ ags, const int* __restrict__ agi,
    float* __restrict__ prm, float* __restrict__ prs, int* __restrict__ pri)
{
    int gid = blockIdx.x * 256 + threadIdx.x;   // 0..2047
    int n = gid >> 6, c = (gid & 63) * 4;
    float4 vm = {-3.4e38f, -3.4e38f, -3.4e38f, -3.4e38f};
    int4   im = {0, 0, 0, 0};
    float4 sm = {0.f, 0.f, 0.f, 0.f};
    for (int ch = 0; ch < NCHUNK; ++ch) {
        long o = ((long)(n * NCHUNK + ch) * CDIM) + c;
        *(float4*)(prm + o) = vm;
        *(int4*)(pri + o)   = im;
        *(float4*)(prs + o) = sm;
        float4 av = *(const float4*)(agm + o);
        float4 as = *(const float4*)(ags + o);
        int4   ai = *(const int4*)(agi + o);
        if (av.x > vm.x) { vm.x = av.x; im.x = ai.x; }   // strict >: earlier chunk wins ties
        if (av.y > vm.y) { vm.y = av.y; im.y = ai.y; }
        if (av.z > vm.z) { vm.z = av.z; im.z = ai.z; }
        if (av.w > vm.w) { vm.w = av.w; im.w = ai.w; }
        sm.x += as.x; sm.y += as.y; sm.z += as.z; sm.w += as.w;
    }
}

// ---------------------------------------------------------------------------
// K4: fused scan + LayerNorm.
//     One wave per (n,chunk): 64 lanes x float4 = 256 c, sequential 32 t.
//     Per t: finish cummax/cumsum, wave-reduce row stats, write LN'd out0,
//     pm back into X (for ACT transpose), ti into Ttmp (for TI transpose).
//     LN(csum*a) = (csum - mu_s) * a / sqrt(a^2 var_s + eps).
// ---------------------------------------------------------------------------
__global__ __launch_bounds__(256) void k_sln(
    float* __restrict__ X,
    const float* __restrict__ prm, const float* __restrict__ prs, const int* __restrict__ pri,
    const float* __restrict__ dvals,
    float* __restrict__ out0, float* __restrict__ Ttmp)
{
    int tid = threadIdx.x;
    int wid = tid >> 6, lane = tid & 63;
    int p = blockIdx.x * 4 + wid;       // 0..2047
    int n = p >> 6, ch = p & 63;
    int t0 = ch * CHLEN;
    int c = lane * 4;

    long o = ((long)(n * NCHUNK + ch) * CDIM) + c;
    float4 vm = *(const float4*)(prm + o);
    int4   im = *(const int4*)(pri + o);
    float4 sm = *(const float4*)(prs + o);

    float4 dvt;
    if (lane < 5) dvt = *(const float4*)(dvals + n * DEMO + lane * 4);

    float* xrow = X + ((long)n * LSEQ + t0) * CDIM + c;

    for (int tt = 0; tt < CHLEN; ++tt) {
        int t = t0 + tt;
        float4 x = *(const float4*)(xrow + (long)tt * CDIM);

        if (x.x > vm.x) { vm.x = x.x; im.x = t; }
        if (x.y > vm.y) { vm.y = x.y; im.y = t; }
        if (x.z > vm.z) { vm.z = x.z; im.z = t; }
        if (x.w > vm.w) { vm.w = x.w; im.w = t; }
        sm.x += x.x; sm.y += x.y; sm.z += x.z; sm.w += x.w;

        bool pad = t < (LSEQ - 1);
        float4 pm;
        pm.x = pad ? fmaxf(vm.x, 0.0f) : vm.x;
        pm.y = pad ? fmaxf(vm.y, 0.0f) : vm.y;
        pm.z = pad ? fmaxf(vm.z, 0.0f) : vm.z;
        pm.w = pad ? fmaxf(vm.w, 0.0f) : vm.w;
        int4 ti;
        ti.x = (pad && vm.x <= 0.0f) ? (t - (LSEQ - 1)) : im.x;
        ti.y = (pad && vm.y <= 0.0f) ? (t - (LSEQ - 1)) : im.y;
        ti.z = (pad && vm.z <= 0.0f) ? (t - (LSEQ - 1)) : im.z;
        ti.w = (pad && vm.w <= 0.0f) ? (t - (LSEQ - 1)) : im.w;

        // row stats over 256 c
        float sum_p = pm.x + pm.y + pm.z + pm.w;
        float sq_p  = pm.x * pm.x + pm.y * pm.y + pm.z * pm.z + pm.w * pm.w;
        float sum_s = sm.x + sm.y + sm.z + sm.w;
        float sq_s  = sm.x * sm.x + sm.y * sm.y + sm.z * sm.z + sm.w * sm.w;
        #pragma unroll
        for (int off = 32; off > 0; off >>= 1) {
            sum_p += __shfl_xor(sum_p, off);
            sq_p  += __shfl_xor(sq_p, off);
            sum_s += __shfl_xor(sum_s, off);
            sq_s  += __shfl_xor(sq_s, off);
        }
        const float inv = 1.0f / 256.0f;
        float mu_p = sum_p * inv;
        float var_p = sq_p * inv - mu_p * mu_p;
        float mu_s = sum_s * inv;
        float var_s = sq_s * inv - mu_s * mu_s;

        float r1 = 1.0f / sqrtf(var_p + LNEPS);
        const float a = 1.0f / 2048.0f;
        float r2 = a / sqrtf(a * a * var_s + LNEPS);
        float b = 1.0f / sqrtf((float)(t + 1));
        float r3 = b / sqrtf(b * b * var_s + LNEPS);

        long row = (long)n * LSEQ + t;
        float* ob = out0 + row * 788;
        float4 o1 = {(pm.x - mu_p) * r1, (pm.y - mu_p) * r1, (pm.z - mu_p) * r1, (pm.w - mu_p) * r1};
        *(float4*)(ob + c) = o1;
        float4 o2 = {(sm.x - mu_s) * r2, (sm.y - mu_s) * r2, (sm.z - mu_s) * r2, (sm.w - mu_s) * r2};
        *(float4*)(ob + 256 + c) = o2;
        float4 o3 = {(sm.x - mu_s) * r3, (sm.y - mu_s) * r3, (sm.z - mu_s) * r3, (sm.w - mu_s) * r3};
        *(float4*)(ob + 512 + c) = o3;
        if (lane < 5) *(float4*)(ob + 768 + lane * 4) = dvt;

        *(float4*)(xrow + (long)tt * CDIM) = pm;   // raw p_max for ACT transpose
        float4 tif = {(float)ti.x, (float)ti.y, (float)ti.z, (float)ti.w};
        *(float4*)(Ttmp + row * CDIM + c) = tif;
    }
}

// ---------------------------------------------------------------------------
// K5: tiled transpose per n: [n, t, c] (2048x256) -> [n, c, t] (256x2048)
// ---------------------------------------------------------------------------
__global__ __launch_bounds__(256) void k_tr(
    const float* __restrict__ src, float* __restrict__ dst)
{
    __shared__ float tile[64][65];
    int n  = blockIdx.z;
    int tB = blockIdx.x;   // 0..31
    int cB = blockIdx.y;   // 0..3
    int tid = threadIdx.x;
    int i0 = tid >> 4;     // 0..15
    int j4 = tid & 15;     // 0..15

    const float* sp = src + ((long)n * LSEQ + tB * 64) * CDIM + cB * 64;
    #pragma unroll
    for (int r = 0; r < 4; ++r) {
        int i = i0 + r * 16;
        float4 v = *(const float4*)(sp + (long)i * CDIM + j4 * 4);
        tile[i][j4 * 4 + 0] = v.x;
        tile[i][j4 * 4 + 1] = v.y;
        tile[i][j4 * 4 + 2] = v.z;
        tile[i][j4 * 4 + 3] = v.w;
    }
    __syncthreads();
    float* dp = dst + ((long)n * CDIM + cB * 64) * LSEQ + tB * 64;
    #pragma unroll
    for (int r = 0; r < 4; ++r) {
        int j = i0 + r * 16;   // c within tile
        float4 v;
        v.x = tile[j4 * 4 + 0][j];
        v.y = tile[j4 * 4 + 1][j];
        v.z = tile[j4 * 4 + 2][j];
        v.w = tile[j4 * 4 + 3][j];
        *(float4*)(dp + (long)j * LSEQ + j4 * 4) = v;
    }
}

// ---------------------------------------------------------------------------
extern "C" void kernel_launch(void* const* d_in, const int* in_sizes, int n_in,
                              void* d_out, int out_size, void* d_ws, size_t ws_size,
                              hipStream_t stream)
{
    const float* dem = (const float*)d_in[0];
    const float* ts0 = (const float*)d_in[1];
    const float* ts1 = (const float*)d_in[2];
    const float* ts2 = (const float*)d_in[3];
    const float* ts3 = (const float*)d_in[4];
    const float* W1  = (const float*)d_in[5];
    const float* b1  = (const float*)d_in[6];
    const float* W2  = (const float*)d_in[7];
    const float* b2  = (const float*)d_in[8];
    const float* Wl  = (const float*)d_in[9];
    const float* bl  = (const float*)d_in[10];

    float* ws = (float*)d_ws;
    float* X    = ws + OFF_X;
    float* agm  = ws + OFF_AGM;
    float* ags  = ws + OFF_AGS;
    int*   agi  = (int*)(ws + OFF_AGI);
    float* prm  = ws + OFF_PRM;
    float* prs  = ws + OFF_PRS;
    int*   pri  = (int*)(ws + OFF_PRI);
    float* dv   = ws + OFF_DV;
    float* base = ws + OFF_BASE;

    float* out    = (float*)d_out;
    float* outTI  = out + OUTTI_OFF;
    float* outACT = out + OUTACT_OFF;

    k_dem<<<1, 256, 0, stream>>>(dem, W1, b1, W2, b2, Wl, bl, dv, base);
    k_gemm<<<NBATCH * 32, 256, 0, stream>>>(ts0, ts1, ts2, ts3, Wl, base, X, agm, ags, agi);
    k_pre<<<8, 256, 0, stream>>>(agm, ags, agi, prm, prs, pri);
    // fused scan+LN: Ttmp (time_inds, [n,t,c]) staged in the outACT section
    k_sln<<<512, 256, 0, stream>>>(X, prm, prs, pri, dv, out, outACT);
    // transpose time_inds: Ttmp [n,t,c] -> outTI [n,c,t]  (before ACT overwrites)
    k_tr<<<dim3(32, 4, 32), 256, 0, stream>>>(outACT, outTI);
    // transpose activations: X (=p_max raw) [n,t,c] -> outACT [n,c,t]
    k_tr<<<dim3(32, 4, 32), 256, 0, stream>>>(X, outACT);
}